// Round 8
// baseline (2916.938 us; speedup 1.0000x reference)
//
#include <hip/hip_runtime.h>
#include <cstdint>

#define T_LEN 2048
#define NB    32
#define NROWS (NB*T_LEN)   // 65536
#define HH    200
#define G4    800
#define TB    256          // LSTM time-chunk (per dispatch)
#define SB    8            // step block staged in LDS

typedef _Float16 f16;
typedef _Float16 f16x2 __attribute__((ext_vector_type(2)));
typedef _Float16 f16x8 __attribute__((ext_vector_type(8)));
typedef float   floatx4 __attribute__((ext_vector_type(4)));

#define GLD_LDS16(g, l) __builtin_amdgcn_global_load_lds( \
    (const __attribute__((address_space(1))) void*)(g), \
    (__attribute__((address_space(3))) void*)(l), 16, 0, 0)

static __device__ __forceinline__ unsigned short f2h(float x) {
  f16 h = (f16)x; return __builtin_bit_cast(unsigned short, h);
}
static __device__ __forceinline__ float dot2f(unsigned int a, unsigned int b, float c) {
  return __builtin_amdgcn_fdot2(__builtin_bit_cast(f16x2, a),
                                __builtin_bit_cast(f16x2, b), c, false);
}
static __device__ __forceinline__ float sigm(float x) {
  return __builtin_amdgcn_rcpf(1.f + __expf(-x));
}
static __device__ __forceinline__ float tanh_fast(float x) {
  return 1.f - 2.f * __builtin_amdgcn_rcpf(__expf(2.f * x) + 1.f);
}

// ---------------- P/Q precompute: P[dt,co]=sum_ci relu(k1)k2, Q with relu(-k1)
__global__ void pq_kernel(const float* __restrict__ k1w, const float* __restrict__ k2w,
                          float* __restrict__ PQ) {
  int id = blockIdx.x * 256 + threadIdx.x;   // 1536 total
  int pq = id / 768;
  int rem = id % 768;
  int wdt = rem / 256;
  int co  = rem % 256;
  float acc = 0.f;
  for (int ci = 0; ci < 256; ++ci) {
    float k = k1w[ci];
    float kk = pq ? fmaxf(-k, 0.f) : fmaxf(k, 0.f);
    acc += kk * k2w[((size_t)wdt * 256 + ci) * 256 + co];
  }
  PQ[id] = acc;
}

// ---------------- f16 weight prep (B matrices stored TRANSPOSED: [n][k])
// K3T[co][ci] ; Wx2[dir][c][k] with permuted col c=4n+q (gate g=q*200+n) ;
// WhS: per-thread k-split weight records [dir][s][n][4 gates][104 halves]
//   (record = 416 halves; gate q at offset q*104; half j of gate q = W[256 + s*104 + j][g],
//    zero-padded where k>=200) ;
// bcat permuted, f-gate +1 folded.
__global__ void prep_kernel(const float* __restrict__ k3w,
                            const float* __restrict__ Wf, const float* __restrict__ bfv,
                            const float* __restrict__ Wb, const float* __restrict__ bbv,
                            unsigned short* __restrict__ K3h, unsigned short* __restrict__ Wx2,
                            unsigned short* __restrict__ WhS, float* __restrict__ bcat) {
  int id = blockIdx.x * 256 + threadIdx.x;
  if (id < 65536) {                      // K3T[co*256+ci] = k3w[ci*256+co]
    K3h[id] = f2h(k3w[(id & 255) * 256 + (id >> 8)]);
    return;
  }
  id -= 65536;
  if (id < 409600) {                     // Wx2[dir][c<800][k<256]
    int dirv = id / 204800;
    int r = id % 204800;
    int c = r >> 8, k = r & 255;
    int n = c >> 2, q = c & 3;
    int g = q * 200 + n;
    const float* W = dirv ? Wb : Wf;
    Wx2[id] = f2h(W[k * 800 + g]);
    return;
  }
  id -= 409600;
  if (id < 332800) {                     // WhS halves: 2*2*200*416
    int rec = id / 416;
    int m   = id % 416;
    int n   = rec % 200;
    int sd  = rec / 200;                 // 0..3
    int s   = sd & 1, dirv = sd >> 1;
    int q   = m / 104, j = m % 104;
    int k   = s * 104 + j;
    float v = 0.f;
    if (k < 200) {
      const float* W = dirv ? Wb : Wf;
      v = W[(256 + k) * 800 + (q * 200 + n)];
    }
    WhS[id] = f2h(v);
    return;
  }
  id -= 332800;
  if (id < 1600) {                       // bcat[dir*800 + c] with same perm; +1 on f gate
    int dirv = id / 800;
    int c = id % 800;
    int n = c >> 2, q = c & 3;
    int g = q * 200 + n;
    bcat[id] = (dirv ? bbv : bfv)[g] + (q == 2 ? 1.f : 0.f);
  }
}

// ---------------- conv2 via rank-1 collapse (6 FMA/elem)
__global__ void conv2_kernel(const float* __restrict__ s, const float* __restrict__ PQ,
                             unsigned short* __restrict__ C2) {
  int row = blockIdx.x;
  int co  = threadIdx.x;
  int t = row & (T_LEN - 1);
  float s0 = s[row];
  float sm = (t > 0)         ? s[row - 1] : 0.f;
  float sp = (t < T_LEN - 1) ? s[row + 1] : 0.f;
  const float* P = PQ;
  const float* Q = PQ + 768;
  float acc = 0.f;
  float a, m;
  a = fmaxf(sm, 0.f); m = fmaxf(-sm, 0.f);
  acc += a * P[0*256+co] + m * Q[0*256+co];
  a = fmaxf(s0, 0.f); m = fmaxf(-s0, 0.f);
  acc += a * P[1*256+co] + m * Q[1*256+co];
  a = fmaxf(sp, 0.f); m = fmaxf(-sp, 0.f);
  acc += a * P[2*256+co] + m * Q[2*256+co];
  C2[(size_t)row * 256 + co] = f2h(fmaxf(acc, 0.f));
}

// ---------------- MFMA GEMM, K=256 fixed. B given TRANSPOSED [n][256].
// mode 0: direct rows; out = relu(acc) + relu(s*k1aw+k1ab)   (conv3+conv1a -> enc)
// mode 2: gathered rows (chain/time-chunk); out = acc + bcat[dir*800+col]
__global__ __launch_bounds__(256, 2) void gemm_kernel(
    const unsigned short* __restrict__ Ag, const unsigned short* __restrict__ Bg0,
    int N, int ntiles, int mode,
    unsigned short* __restrict__ Outp,
    const float* __restrict__ bias, const float* __restrict__ Sg,
    const float* __restrict__ k1aw, const float* __restrict__ k1ab,
    const int* __restrict__ lens, int t0)
{
  __shared__ __align__(16) unsigned short Bl[128*128]; // [n][k-phase], xor-swizzled 16B chunks
  __shared__ __align__(16) unsigned short Al[128*40];  // [m][k32], pad 40 halves
  __shared__ int rowsrc[128];
  int tid = threadIdx.x;
  int tm = blockIdx.x / ntiles, tn = blockIdx.x % ntiles;
  int col0 = tn * 128;
  int lane = tid & 63, wv = tid >> 6;
  int quad = lane >> 4, l16 = lane & 15;
  int wrow = (wv & 1) * 64, wcol = (wv >> 1) * 64;

  int dirv = 0;
  if (mode == 2) dirv = ((tm * 128) >> 8) >> 5;   // chain = m/TB ; dir = chain>>5
  const unsigned short* Bg = Bg0 + (size_t)dirv * 204800;

  if (tid < 128) {
    int r;
    if (mode == 2) {
      int m = tm * 128 + tid;
      int ch = m >> 8;              // TB=256
      int ls = m & 255;
      int b = ch & 31, dd = ch >> 5;
      int L = lens[b]; L = (L < 0) ? 0 : ((L > T_LEN) ? T_LEN : L);
      int t = t0 + ls;
      int src = dd ? (L - 1 - t) : t;
      src = (src < 0) ? 0 : ((src > T_LEN - 1) ? (T_LEN - 1) : src);
      r = b * T_LEN + src;
    } else {
      r = tm * 128 + tid;
    }
    rowsrc[tid] = r;
  }

  floatx4 acc[16];
  #pragma unroll
  for (int i = 0; i < 16; ++i) acc[i] = (floatx4){0.f,0.f,0.f,0.f};

  for (int ph = 0; ph < 2; ++ph) {
    __syncthreads();
    // stage B half-panel from BT: rows n in [col0,col0+128), k in [ph*128, +128)
    #pragma unroll
    for (int it = 0; it < 8; ++it) {
      int idx = it * 256 + tid;             // 2048 b128 chunks
      int n  = idx >> 4;                    // 0..127 local col
      int k8 = idx & 15;                    // 16B chunk within phase
      int nn = col0 + n;
      uint4 v = (uint4){0u,0u,0u,0u};
      if (nn < N) v = *(const uint4*)(Bg + (size_t)nn * 256 + ph * 128 + k8 * 8);
      *(uint4*)(&Bl[n * 128 + ((k8 ^ (n & 7)) * 8)]) = v;
    }
    for (int kb2 = 0; kb2 < 4; ++kb2) {
      int kb = ph * 4 + kb2;
      __syncthreads();
      #pragma unroll
      for (int i = 0; i < 2; ++i) {
        int c2 = i * 256 + tid;
        int r = c2 >> 2, kc = (c2 & 3) * 8;
        uint4 v = *(const uint4*)(Ag + (size_t)rowsrc[r] * 256 + kb * 32 + kc);
        *(uint4*)(&Al[r * 40 + kc]) = v;
      }
      __syncthreads();
      f16x8 af[4], bfr[4];
      #pragma unroll
      for (int mt = 0; mt < 4; ++mt)
        af[mt] = *(const f16x8*)(&Al[(wrow + mt*16 + l16) * 40 + quad * 8]);
      #pragma unroll
      for (int nt = 0; nt < 4; ++nt) {
        int nl = wcol + nt*16 + l16;
        int c = kb2 * 4 + quad;
        bfr[nt] = *(const f16x8*)(&Bl[nl * 128 + ((c ^ (nl & 7)) * 8)]);
      }
      #pragma unroll
      for (int mt = 0; mt < 4; ++mt)
        #pragma unroll
        for (int nt = 0; nt < 4; ++nt)
          acc[mt*4+nt] = __builtin_amdgcn_mfma_f32_16x16x32_f16(af[mt], bfr[nt], acc[mt*4+nt], 0, 0, 0);
    }
  }
  #pragma unroll
  for (int mt = 0; mt < 4; ++mt) {
    #pragma unroll
    for (int nt = 0; nt < 4; ++nt) {
      floatx4 v = acc[mt*4+nt];
      int col = col0 + wcol + nt*16 + l16;
      if (col < N) {
        #pragma unroll
        for (int r = 0; r < 4; ++r) {
          int row = tm * 128 + wrow + mt*16 + quad*4 + r;
          float x = v[r];
          float o;
          if (mode == 0) {
            float sv = Sg[row];
            float a1 = sv * k1aw[col] + k1ab[col];
            o = fmaxf(x, 0.f) + fmaxf(a1, 0.f);
          } else {
            o = x + bias[dirv * 800 + col];
          }
          Outp[(size_t)row * N + col] = f2h(o);
        }
      }
    }
  }
}

// ---------------- k-split dot2 recurrent LSTM: one WG per (sample, direction), 448 thr
// Worker t<400: unit n=t%200, k-half s=t/200 (s=0: k 0..103, s=1: k 104..207, zero pad).
// Each worker computes partials of ALL FOUR gates of its unit over its k-half:
//   13 b128 broadcast h-reads + 208 dot2. s=1 sends float4 partials via LDS;
//   s=0 adds, does 1x-redundant activation locally. 2 barriers/step.
// WEIGHT RESIDENCY FIX (R7 post-mortem): every prior round ran at VGPR_Count 116-128
// because the register allocator REMATERIALIZES loop-invariant const loads inside the
// step loop (re-streaming ~330KB/step/WG from L2 — the ~2850 cyc/step invariant).
// The one-time asm pin AFTER the load makes each w[] value an asm output, which
// cannot be rematerialized by re-loading -> must stay register-resident.
// 448 thr = 7 waves; pool 2048 VGPR/CU -> up to 292 regs/wave; need ~270.
__global__ __launch_bounds__(448, 1)
void lstm_kernel(
    const unsigned short* __restrict__ XWbuf,  // [64][TB][800] f16, cols c=4n+q, bias(+1 f) folded
    const unsigned short* __restrict__ WhS,    // k-split weight records (see prep)
    const int* __restrict__ lens,
    unsigned short* __restrict__ fwH, unsigned short* __restrict__ bwH,
    float* __restrict__ cState, unsigned short* __restrict__ hState,
    int t0)
{
  int ch  = blockIdx.x;
  int dir = ch >> 5;
  int b   = ch & 31;
  int L = lens[b];
  L = (L < 0) ? 0 : ((L > T_LEN) ? T_LEN : L);
  int tend = t0 + TB; if (tend > L) tend = L;
  int tid = threadIdx.x;
  bool worker = tid < 400;
  int s = (tid >= 200) ? 1 : 0;
  int n = tid - s * 200;

  __shared__ __align__(16) unsigned short xw_lds[2][SB*800]; // 25.6 KB
  __shared__ __align__(16) unsigned short hist[SB*200];      // 3.2 KB
  __shared__ __align__(16) unsigned short himg[2][208];      // linear h + pad, dbuf
  __shared__ __align__(16) floatx4 zpair[200];               // 3.2 KB partial-z exchange

  // zero both h buffers (incl. pad 200..207)
  if (tid < 208) ((unsigned int*)himg)[tid] = 0u;

  float c = 0.f;
  unsigned short last_h = 0;
  if (tid < 200 && t0 > 0) {
    c = cState[ch * HH + tid];
    last_h = hState[ch * HH + tid];
  }
  __syncthreads();
  if (tid < 200 && t0 > 0) himg[0][tid] = last_h;

  // persistent k-split weights: 4 gates x 52 dwords, compile-time indexed.
  // Pin ONCE after the load: output-of-asm values are non-rematerializable.
  unsigned int w[208];
  if (worker) {
    const uint4* wp = (const uint4*)(WhS + ((size_t)((dir * 2 + s) * 200 + n)) * 416);
    #pragma unroll
    for (int r = 0; r < 52; ++r) {
      uint4 v = wp[r];
      w[4*r+0] = v.x; w[4*r+1] = v.y; w[4*r+2] = v.z; w[4*r+3] = v.w;
    }
    #pragma unroll
    for (int r = 0; r < 208; ++r)
      asm volatile("" : "+v"(w[r]));
  }

  unsigned short* Hd = dir ? bwH : fwH;
  const unsigned short* XWc = XWbuf + ((size_t)ch * TB) * 800;

  // DMA block 0 into xw_lds[0]
  if (t0 < tend) {
    #pragma unroll
    for (int it = 0; it < 2; ++it) {
      int cidx = it * 448 + tid;
      if (cidx < 800)
        GLD_LDS16(XWc + (size_t)cidx * 8, &xw_lds[0][cidx * 8]);
    }
  }
  __syncthreads();   // drains DMA; h state visible

  int buf = 0, cur = 0;
  int prev_tb = -1, prev_cnt = 0;

#define DOT4(rr, dd, hv_d) { \
    a0 = dot2f(hv_d, w[0*52 + (rr)*4 + (dd)], a0); \
    a1 = dot2f(hv_d, w[1*52 + (rr)*4 + (dd)], a1); \
    a2 = dot2f(hv_d, w[2*52 + (rr)*4 + (dd)], a2); \
    a3 = dot2f(hv_d, w[3*52 + (rr)*4 + (dd)], a3); }

  for (int tb = t0; tb < tend; tb += SB) {
    int cnt = tend - tb; if (cnt > SB) cnt = SB;
    for (int sl = 0; sl < cnt; ++sl) {
      if (sl == 0) {
        // DMA next block into the other buffer (drains at a later barrier)
        int ntb = tb + SB;
        if ((ntb - t0) < TB) {
          const unsigned short* src = XWc + (size_t)(ntb - t0) * 800;
          #pragma unroll
          for (int it = 0; it < 2; ++it) {
            int cidx = it * 448 + tid;
            if (cidx < 800)
              GLD_LDS16(src + (size_t)cidx * 8, &xw_lds[buf ^ 1][cidx * 8]);
          }
        }
        // flush previous block's h history
        if (prev_tb >= 0) {
          int pcnt = prev_cnt;
          if (tid < pcnt * 25) {
            int srow = dir ? (pcnt - 1 - tid / 25) : (tid / 25);
            uint4 v = *(const uint4*)&hist[srow*200 + (tid % 25)*8];
            size_t base = dir ? ((size_t)(b*T_LEN + (L - prev_tb - pcnt)))*HH
                              : ((size_t)(b*T_LEN + prev_tb))*HH;
            *(uint4*)(Hd + base + (size_t)tid*8) = v;
          }
        }
      }
      float a0 = 0.f, a1 = 0.f, a2 = 0.f, a3 = 0.f;
      if (worker) {
        const uint4* hp = (const uint4*)(&himg[cur][s * 104]);
        #pragma unroll
        for (int r = 0; r < 13; ++r) {
          uint4 hv = hp[r];
          DOT4(r, 0, hv.x)
          DOT4(r, 1, hv.y)
          DOT4(r, 2, hv.z)
          DOT4(r, 3, hv.w)
        }
        if (s == 1) {
          floatx4 z; z[0] = a0; z[1] = a1; z[2] = a2; z[3] = a3;
          zpair[n] = z;
        }
      }
      __syncthreads();   // partials visible; himg[cur] reads complete
      if (worker && s == 0) {
        floatx4 p = zpair[n];
        uint2 xv = *(const uint2*)&xw_lds[buf][sl*800 + 4*n];
        f16x2 xa = __builtin_bit_cast(f16x2, xv.x);
        f16x2 xb = __builtin_bit_cast(f16x2, xv.y);
        float zi = a0 + p[0] + (float)xa[0];
        float zj = a1 + p[1] + (float)xa[1];
        float zf = a2 + p[2] + (float)xb[0];
        float zo = a3 + p[3] + (float)xb[1];
        c = c * sigm(zf) + sigm(zi) * tanh_fast(zj);
        float h = tanh_fast(c) * sigm(zo);
        unsigned short hh = f2h(h);
        last_h = hh;
        himg[cur ^ 1][n] = hh;
        hist[sl*200 + n] = hh;
      }
      cur ^= 1;
      __syncthreads();   // new h visible for next step
    }
    prev_tb = tb; prev_cnt = cnt; buf ^= 1;
  }
#undef DOT4
  // final flush + state save
  if (prev_tb >= 0) {
    int pcnt = prev_cnt;
    if (tid < pcnt * 25) {
      int srow = dir ? (pcnt - 1 - tid / 25) : (tid / 25);
      uint4 v = *(const uint4*)&hist[srow*200 + (tid % 25)*8];
      size_t base = dir ? ((size_t)(b*T_LEN + (L - prev_tb - pcnt)))*HH
                        : ((size_t)(b*T_LEN + prev_tb))*HH;
      *(uint4*)(Hd + base + (size_t)tid*8) = v;
    }
  }
  if (tid < 200) {
    cState[ch * HH + tid] = c;
    hState[ch * HH + tid] = last_h;
  }
}

// ---------------- logits = [fwH|bwH] @ Wd + bd
__global__ __launch_bounds__(256) void out_kernel(
    const unsigned short* __restrict__ fwH, const unsigned short* __restrict__ bwH,
    const float* __restrict__ Wd, const float* __restrict__ bd, float* __restrict__ out)
{
  __shared__ float wd[2000];
  int tid = threadIdx.x;
  for (int i = tid; i < 2000; i += 256) wd[i] = Wd[i];
  __syncthreads();
  int row = blockIdx.x * 256 + tid;
  float acc0 = bd[0], acc1 = bd[1], acc2 = bd[2], acc3 = bd[3], acc4 = bd[4];
  const unsigned int* fu = (const unsigned int*)(fwH + (size_t)row * HH);
  const unsigned int* bu = (const unsigned int*)(bwH + (size_t)row * HH);
  #pragma unroll 4
  for (int i = 0; i < 100; ++i) {
    f16x2 pf = __builtin_bit_cast(f16x2, fu[i]);
    f16x2 pb = __builtin_bit_cast(f16x2, bu[i]);
    int k = 2 * i;
    float f0 = (float)pf[0], f1 = (float)pf[1];
    float b0 = (float)pb[0], b1 = (float)pb[1];
    const float* w0 = &wd[k*5];
    const float* w1 = &wd[(k+1)*5];
    const float* w2 = &wd[(200+k)*5];
    const float* w3 = &wd[(201+k)*5];
    acc0 += f0*w0[0] + f1*w1[0] + b0*w2[0] + b1*w3[0];
    acc1 += f0*w0[1] + f1*w1[1] + b0*w2[1] + b1*w3[1];
    acc2 += f0*w0[2] + f1*w1[2] + b0*w2[2] + b1*w3[2];
    acc3 += f0*w0[3] + f1*w1[3] + b0*w2[3] + b1*w3[3];
    acc4 += f0*w0[4] + f1*w1[4] + b0*w2[4] + b1*w3[4];
  }
  float* o = out + (size_t)row * 5;
  o[0]=acc0; o[1]=acc1; o[2]=acc2; o[3]=acc3; o[4]=acc4;
}

extern "C" void kernel_launch(void* const* d_in, const int* in_sizes, int n_in,
                              void* d_out, int out_size, void* d_ws, size_t ws_size,
                              hipStream_t stream)
{
  const float* signals = (const float*)d_in[0];
  const int*   lens    = (const int*)  d_in[1];
  const float* k1w     = (const float*)d_in[2];
  const float* k1aw    = (const float*)d_in[3];
  const float* k1ab    = (const float*)d_in[4];
  const float* k2w     = (const float*)d_in[5];
  const float* k3w     = (const float*)d_in[6];
  const float* Wf      = (const float*)d_in[7];
  const float* bf      = (const float*)d_in[8];
  const float* Wb      = (const float*)d_in[9];
  const float* bb      = (const float*)d_in[10];
  const float* Wd      = (const float*)d_in[11];
  const float* bd      = (const float*)d_in[12];
  float* out = (float*)d_out;
  char* ws = (char*)d_ws;

  // Region A aliases C2 (conv phase) and XWbuf (LSTM phase) — disjoint lifetimes.
  size_t szC2   = (size_t)NROWS * 256 * 2;          // 33,554,432
  size_t szXWb  = (size_t)64 * TB * 800 * 2;        // 26,214,400
  size_t szA    = (szC2 > szXWb) ? szC2 : szXWb;
  size_t oA   = 0;
  size_t oE   = oA   + szA;
  size_t oFw  = oE   + (size_t)NROWS*256*2;
  size_t oBw  = oFw  + (size_t)NROWS*HH*2;
  size_t oWhS = oBw  + (size_t)NROWS*HH*2;
  size_t oWx2 = oWhS + (size_t)332800*2;            // 665,600
  size_t oK3  = oWx2 + (size_t)2*256*800*2;
  size_t oPQ  = oK3  + (size_t)256*256*2;
  size_t oBc  = oPQ  + 1536*4;
  size_t oCst = oBc  + 1600*4;
  size_t oHst = oCst + (size_t)64*HH*4;
  size_t total= oHst + (size_t)64*HH*2;
  if (ws_size < total) return;

  unsigned short* C2    = (unsigned short*)(ws + oA);
  unsigned short* XWbuf = (unsigned short*)(ws + oA);
  unsigned short* E     = (unsigned short*)(ws + oE);
  unsigned short* fwH   = (unsigned short*)(ws + oFw);
  unsigned short* bwH   = (unsigned short*)(ws + oBw);
  unsigned short* WhS   = (unsigned short*)(ws + oWhS);
  unsigned short* Wx2   = (unsigned short*)(ws + oWx2);
  unsigned short* K3h   = (unsigned short*)(ws + oK3);
  float* PQ     = (float*)(ws + oPQ);
  float* bcat   = (float*)(ws + oBc);
  float* cState = (float*)(ws + oCst);
  unsigned short* hState = (unsigned short*)(ws + oHst);

  (void)hipMemsetAsync(fwH, 0, (size_t)2*NROWS*HH*2, stream);
  pq_kernel  <<<6,     256, 0, stream>>>(k1w, k2w, PQ);
  prep_kernel<<<3163,  256, 0, stream>>>(k3w, Wf, bf, Wb, bb, K3h, Wx2, WhS, bcat);
  conv2_kernel<<<NROWS, 256, 0, stream>>>(signals, PQ, C2);
  gemm_kernel<<<1024,  256, 0, stream>>>(C2, K3h, 256, 2, 0, E, nullptr, signals, k1aw, k1ab, nullptr, 0);
  for (int t0 = 0; t0 < T_LEN; t0 += TB) {
    gemm_kernel<<<896, 256, 0, stream>>>(E, Wx2, 800, 7, 2, XWbuf, bcat, nullptr, nullptr, nullptr, lens, t0);
    lstm_kernel<<<64,  448, 0, stream>>>(XWbuf, WhS, lens, fwH, bwH, cState, hState, t0);
  }
  out_kernel <<<256,   256, 0, stream>>>(fwH, bwH, Wd, bd, out);
}

// Round 9
// 2573.300 us; speedup vs baseline: 1.1335x; 1.1335x over previous
//
#include <hip/hip_runtime.h>
#include <cstdint>

#define T_LEN 2048
#define NB    32
#define NROWS (NB*T_LEN)   // 65536
#define HH    200
#define G4    800
#define TB    256          // LSTM time-chunk (per dispatch)
#define SB    8            // step block staged in LDS

typedef _Float16 f16;
typedef _Float16 f16x2 __attribute__((ext_vector_type(2)));
typedef _Float16 f16x8 __attribute__((ext_vector_type(8)));
typedef float   floatx4 __attribute__((ext_vector_type(4)));

#define GLD_LDS16(g, l) __builtin_amdgcn_global_load_lds( \
    (const __attribute__((address_space(1))) void*)(g), \
    (__attribute__((address_space(3))) void*)(l), 16, 0, 0)

static __device__ __forceinline__ unsigned short f2h(float x) {
  f16 h = (f16)x; return __builtin_bit_cast(unsigned short, h);
}
static __device__ __forceinline__ float dot2f(unsigned int a, unsigned int b, float c) {
  return __builtin_amdgcn_fdot2(__builtin_bit_cast(f16x2, a),
                                __builtin_bit_cast(f16x2, b), c, false);
}
static __device__ __forceinline__ float sigm(float x) {
  return __builtin_amdgcn_rcpf(1.f + __expf(-x));
}
static __device__ __forceinline__ float tanh_fast(float x) {
  return 1.f - 2.f * __builtin_amdgcn_rcpf(__expf(2.f * x) + 1.f);
}

// ---------------- P/Q precompute: P[dt,co]=sum_ci relu(k1)k2, Q with relu(-k1)
__global__ void pq_kernel(const float* __restrict__ k1w, const float* __restrict__ k2w,
                          float* __restrict__ PQ) {
  int id = blockIdx.x * 256 + threadIdx.x;   // 1536 total
  int pq = id / 768;
  int rem = id % 768;
  int wdt = rem / 256;
  int co  = rem % 256;
  float acc = 0.f;
  for (int ci = 0; ci < 256; ++ci) {
    float k = k1w[ci];
    float kk = pq ? fmaxf(-k, 0.f) : fmaxf(k, 0.f);
    acc += kk * k2w[((size_t)wdt * 256 + ci) * 256 + co];
  }
  PQ[id] = acc;
}

// ---------------- f16 weight prep (B matrices stored TRANSPOSED: [n][k])
// K3T[co][ci] ; Wx2[dir][c][k] with permuted col c=4n+q (gate g=q*200+n) ;
// WhK: per-thread 5-way k-chunk weight records [dir][s<5][n<200][4 gates][40 halves]
//   (record = 160 halves = 80 dwords; half j of gate q = W[256 + s*40 + j][g]; 5x40=200,
//    no padding) ;
// bcat permuted, f-gate +1 folded.
__global__ void prep_kernel(const float* __restrict__ k3w,
                            const float* __restrict__ Wf, const float* __restrict__ bfv,
                            const float* __restrict__ Wb, const float* __restrict__ bbv,
                            unsigned short* __restrict__ K3h, unsigned short* __restrict__ Wx2,
                            unsigned short* __restrict__ WhK, float* __restrict__ bcat) {
  int id = blockIdx.x * 256 + threadIdx.x;
  if (id < 65536) {                      // K3T[co*256+ci] = k3w[ci*256+co]
    K3h[id] = f2h(k3w[(id & 255) * 256 + (id >> 8)]);
    return;
  }
  id -= 65536;
  if (id < 409600) {                     // Wx2[dir][c<800][k<256]
    int dirv = id / 204800;
    int r = id % 204800;
    int c = r >> 8, k = r & 255;
    int n = c >> 2, q = c & 3;
    int g = q * 200 + n;
    const float* W = dirv ? Wb : Wf;
    Wx2[id] = f2h(W[k * 800 + g]);
    return;
  }
  id -= 409600;
  if (id < 320000) {                     // WhK halves: 2*5*200*160
    int rec = id / 160;
    int m   = id % 160;
    int g   = m / 40, j = m % 40;
    int n   = rec % 200;
    int t2  = rec / 200;                 // 0..9
    int s   = t2 % 5, dirv = t2 / 5;
    int k   = s * 40 + j;
    const float* W = dirv ? Wb : Wf;
    WhK[id] = f2h(W[(256 + k) * 800 + (g * 200 + n)]);
    return;
  }
  id -= 320000;
  if (id < 1600) {                       // bcat[dir*800 + c] with same perm; +1 on f gate
    int dirv = id / 800;
    int c = id % 800;
    int n = c >> 2, q = c & 3;
    int g = q * 200 + n;
    bcat[id] = (dirv ? bbv : bfv)[g] + (q == 2 ? 1.f : 0.f);
  }
}

// ---------------- conv2 via rank-1 collapse (6 FMA/elem)
__global__ void conv2_kernel(const float* __restrict__ s, const float* __restrict__ PQ,
                             unsigned short* __restrict__ C2) {
  int row = blockIdx.x;
  int co  = threadIdx.x;
  int t = row & (T_LEN - 1);
  float s0 = s[row];
  float sm = (t > 0)         ? s[row - 1] : 0.f;
  float sp = (t < T_LEN - 1) ? s[row + 1] : 0.f;
  const float* P = PQ;
  const float* Q = PQ + 768;
  float acc = 0.f;
  float a, m;
  a = fmaxf(sm, 0.f); m = fmaxf(-sm, 0.f);
  acc += a * P[0*256+co] + m * Q[0*256+co];
  a = fmaxf(s0, 0.f); m = fmaxf(-s0, 0.f);
  acc += a * P[1*256+co] + m * Q[1*256+co];
  a = fmaxf(sp, 0.f); m = fmaxf(-sp, 0.f);
  acc += a * P[2*256+co] + m * Q[2*256+co];
  C2[(size_t)row * 256 + co] = f2h(fmaxf(acc, 0.f));
}

// ---------------- MFMA GEMM, K=256 fixed. B given TRANSPOSED [n][256].
// mode 0: direct rows; out = relu(acc) + relu(s*k1aw+k1ab)   (conv3+conv1a -> enc)
// mode 2: gathered rows (chain/time-chunk); out = acc + bcat[dir*800+col]
__global__ __launch_bounds__(256, 2) void gemm_kernel(
    const unsigned short* __restrict__ Ag, const unsigned short* __restrict__ Bg0,
    int N, int ntiles, int mode,
    unsigned short* __restrict__ Outp,
    const float* __restrict__ bias, const float* __restrict__ Sg,
    const float* __restrict__ k1aw, const float* __restrict__ k1ab,
    const int* __restrict__ lens, int t0)
{
  __shared__ __align__(16) unsigned short Bl[128*128]; // [n][k-phase], xor-swizzled 16B chunks
  __shared__ __align__(16) unsigned short Al[128*40];  // [m][k32], pad 40 halves
  __shared__ int rowsrc[128];
  int tid = threadIdx.x;
  int tm = blockIdx.x / ntiles, tn = blockIdx.x % ntiles;
  int col0 = tn * 128;
  int lane = tid & 63, wv = tid >> 6;
  int quad = lane >> 4, l16 = lane & 15;
  int wrow = (wv & 1) * 64, wcol = (wv >> 1) * 64;

  int dirv = 0;
  if (mode == 2) dirv = ((tm * 128) >> 8) >> 5;   // chain = m/TB ; dir = chain>>5
  const unsigned short* Bg = Bg0 + (size_t)dirv * 204800;

  if (tid < 128) {
    int r;
    if (mode == 2) {
      int m = tm * 128 + tid;
      int ch = m >> 8;              // TB=256
      int ls = m & 255;
      int b = ch & 31, dd = ch >> 5;
      int L = lens[b]; L = (L < 0) ? 0 : ((L > T_LEN) ? T_LEN : L);
      int t = t0 + ls;
      int src = dd ? (L - 1 - t) : t;
      src = (src < 0) ? 0 : ((src > T_LEN - 1) ? (T_LEN - 1) : src);
      r = b * T_LEN + src;
    } else {
      r = tm * 128 + tid;
    }
    rowsrc[tid] = r;
  }

  floatx4 acc[16];
  #pragma unroll
  for (int i = 0; i < 16; ++i) acc[i] = (floatx4){0.f,0.f,0.f,0.f};

  for (int ph = 0; ph < 2; ++ph) {
    __syncthreads();
    // stage B half-panel from BT: rows n in [col0,col0+128), k in [ph*128, +128)
    #pragma unroll
    for (int it = 0; it < 8; ++it) {
      int idx = it * 256 + tid;             // 2048 b128 chunks
      int n  = idx >> 4;                    // 0..127 local col
      int k8 = idx & 15;                    // 16B chunk within phase
      int nn = col0 + n;
      uint4 v = (uint4){0u,0u,0u,0u};
      if (nn < N) v = *(const uint4*)(Bg + (size_t)nn * 256 + ph * 128 + k8 * 8);
      *(uint4*)(&Bl[n * 128 + ((k8 ^ (n & 7)) * 8)]) = v;
    }
    for (int kb2 = 0; kb2 < 4; ++kb2) {
      int kb = ph * 4 + kb2;
      __syncthreads();
      #pragma unroll
      for (int i = 0; i < 2; ++i) {
        int c2 = i * 256 + tid;
        int r = c2 >> 2, kc = (c2 & 3) * 8;
        uint4 v = *(const uint4*)(Ag + (size_t)rowsrc[r] * 256 + kb * 32 + kc);
        *(uint4*)(&Al[r * 40 + kc]) = v;
      }
      __syncthreads();
      f16x8 af[4], bfr[4];
      #pragma unroll
      for (int mt = 0; mt < 4; ++mt)
        af[mt] = *(const f16x8*)(&Al[(wrow + mt*16 + l16) * 40 + quad * 8]);
      #pragma unroll
      for (int nt = 0; nt < 4; ++nt) {
        int nl = wcol + nt*16 + l16;
        int c = kb2 * 4 + quad;
        bfr[nt] = *(const f16x8*)(&Bl[nl * 128 + ((c ^ (nl & 7)) * 8)]);
      }
      #pragma unroll
      for (int mt = 0; mt < 4; ++mt)
        #pragma unroll
        for (int nt = 0; nt < 4; ++nt)
          acc[mt*4+nt] = __builtin_amdgcn_mfma_f32_16x16x32_f16(af[mt], bfr[nt], acc[mt*4+nt], 0, 0, 0);
    }
  }
  #pragma unroll
  for (int mt = 0; mt < 4; ++mt) {
    #pragma unroll
    for (int nt = 0; nt < 4; ++nt) {
      floatx4 v = acc[mt*4+nt];
      int col = col0 + wcol + nt*16 + l16;
      if (col < N) {
        #pragma unroll
        for (int r = 0; r < 4; ++r) {
          int row = tm * 128 + wrow + mt*16 + quad*4 + r;
          float x = v[r];
          float o;
          if (mode == 0) {
            float sv = Sg[row];
            float a1 = sv * k1aw[col] + k1ab[col];
            o = fmaxf(x, 0.f) + fmaxf(a1, 0.f);
          } else {
            o = x + bias[dirv * 800 + col];
          }
          Outp[(size_t)row * N + col] = f2h(o);
        }
      }
    }
  }
}

// ---------------- 5-way k-chunk dot2 recurrent LSTM: one WG per (sample, direction),
// 1024 thr (16 waves). Worker tid<1000: s = tid/200 (k-chunk [40s,40s+40)), n = tid%200.
// Each worker: partials of ALL FOUR gates of unit n over its 40-k chunk = 80 dot2,
// 5 broadcast b128 h-reads. s>0 write float4 partials to LDS; s=0 (tid<200) sums 4
// partials + own, does activation. 2 barriers/step.
// WHY 80 dwords/thread: R0-R7 all demanded 200-208 w-dwords -> compiler parked w[] in
// AGPRs and re-read via v_accvgpr moves EVERY step (~650-1000 VALU cyc/step/SIMD tax,
// the 2870-cyc invariant; VGPR_Count pinned at 116-128 arch regs throughout).
// 80 w + ~35 live misc ~ 115 fits the 128-VGPR class at 16 waves -> no AGPR tax.
__global__ __launch_bounds__(1024, 4)
void lstm_kernel(
    const unsigned short* __restrict__ XWbuf,  // [64][TB][800] f16, cols c=4n+q, bias(+1 f) folded
    const unsigned short* __restrict__ WhK,    // 5-way k-chunk weight records (see prep)
    const int* __restrict__ lens,
    unsigned short* __restrict__ fwH, unsigned short* __restrict__ bwH,
    float* __restrict__ cState, unsigned short* __restrict__ hState,
    int t0)
{
  int ch  = blockIdx.x;
  int dir = ch >> 5;
  int b   = ch & 31;
  int L = lens[b];
  L = (L < 0) ? 0 : ((L > T_LEN) ? T_LEN : L);
  int tend = t0 + TB; if (tend > L) tend = L;
  int tid = threadIdx.x;
  bool worker = tid < 1000;
  int s = tid / 200;                    // k-chunk (workers)
  int n = tid - s * 200;                // unit (workers)

  __shared__ __align__(16) unsigned short xw_lds[2][SB*800]; // 25.6 KB
  __shared__ __align__(16) unsigned short hist[SB*200];      // 3.2 KB
  __shared__ __align__(16) unsigned short himg[2][200];      // linear h, dbuf (800 B)
  __shared__ __align__(16) floatx4 zp[800];                  // 12.8 KB partial-z (s=1..4)

  // zero both h buffers
  if (tid < 200) ((unsigned int*)himg)[tid] = 0u;

  float c = 0.f;
  unsigned short last_h = 0;
  if (tid < 200 && t0 > 0) {
    c = cState[ch * HH + tid];
    last_h = hState[ch * HH + tid];
  }
  __syncthreads();
  if (tid < 200 && t0 > 0) himg[0][tid] = last_h;

  // persistent weights: 4 gates x 20 dwords = 80 dwords, compile-time indexed.
  // One-time pin: asm-output values can't be rematerialized by re-loading.
  unsigned int w[80];
  if (worker) {
    const uint4* wp = (const uint4*)(WhK + ((size_t)((dir * 5 + s) * 200 + n)) * 160);
    #pragma unroll
    for (int r = 0; r < 20; ++r) {
      uint4 v = wp[r];
      w[4*r+0] = v.x; w[4*r+1] = v.y; w[4*r+2] = v.z; w[4*r+3] = v.w;
    }
    #pragma unroll
    for (int r = 0; r < 80; ++r)
      asm volatile("" : "+v"(w[r]));
  }

  unsigned short* Hd = dir ? bwH : fwH;
  const unsigned short* XWc = XWbuf + ((size_t)ch * TB) * 800;

  // DMA block 0 into xw_lds[0] (1024 threads cover 800 chunks in one shot)
  if (t0 < tend && tid < 800)
    GLD_LDS16(XWc + (size_t)tid * 8, &xw_lds[0][tid * 8]);
  __syncthreads();   // drains DMA; h state visible

  int buf = 0, cur = 0;
  int prev_tb = -1, prev_cnt = 0;

  for (int tb = t0; tb < tend; tb += SB) {
    int cnt = tend - tb; if (cnt > SB) cnt = SB;
    for (int sl = 0; sl < cnt; ++sl) {
      if (sl == 0) {
        // DMA next block into the other buffer (drains at a later barrier)
        int ntb = tb + SB;
        if ((ntb - t0) < TB && tid < 800) {
          const unsigned short* src = XWc + (size_t)(ntb - t0) * 800;
          GLD_LDS16(src + (size_t)tid * 8, &xw_lds[buf ^ 1][tid * 8]);
        }
        // flush previous block's h history
        if (prev_tb >= 0) {
          int pcnt = prev_cnt;
          if (tid < pcnt * 25) {
            int srow = dir ? (pcnt - 1 - tid / 25) : (tid / 25);
            uint4 v = *(const uint4*)&hist[srow*200 + (tid % 25)*8];
            size_t base = dir ? ((size_t)(b*T_LEN + (L - prev_tb - pcnt)))*HH
                              : ((size_t)(b*T_LEN + prev_tb))*HH;
            *(uint4*)(Hd + base + (size_t)tid*8) = v;
          }
        }
      }
      float a0 = 0.f, a1 = 0.f, a2 = 0.f, a3 = 0.f;
      if (worker) {
        // 5 broadcast b128 reads of this chunk's h slice (wave-uniform addr per s)
        const uint4* hp = (const uint4*)(&himg[cur][s * 40]);
        uint4 h0 = hp[0], h1 = hp[1], h2 = hp[2], h3 = hp[3], h4 = hp[4];
        unsigned int hd[20];
        hd[0]=h0.x;  hd[1]=h0.y;  hd[2]=h0.z;  hd[3]=h0.w;
        hd[4]=h1.x;  hd[5]=h1.y;  hd[6]=h1.z;  hd[7]=h1.w;
        hd[8]=h2.x;  hd[9]=h2.y;  hd[10]=h2.z; hd[11]=h2.w;
        hd[12]=h3.x; hd[13]=h3.y; hd[14]=h3.z; hd[15]=h3.w;
        hd[16]=h4.x; hd[17]=h4.y; hd[18]=h4.z; hd[19]=h4.w;
        #pragma unroll
        for (int d = 0; d < 20; ++d) {
          a0 = dot2f(hd[d], w[0*20 + d], a0);
          a1 = dot2f(hd[d], w[1*20 + d], a1);
          a2 = dot2f(hd[d], w[2*20 + d], a2);
          a3 = dot2f(hd[d], w[3*20 + d], a3);
        }
        if (s != 0) {
          floatx4 z; z[0] = a0; z[1] = a1; z[2] = a2; z[3] = a3;
          zp[(s - 1) * 200 + n] = z;
        }
      }
      __syncthreads();   // partials visible; himg[cur] reads complete
      if (tid < 200) {   // s==0 worker, n == tid
        floatx4 p0 = zp[tid], p1 = zp[200 + tid], p2 = zp[400 + tid], p3 = zp[600 + tid];
        uint2 xv = *(const uint2*)&xw_lds[buf][sl*800 + 4*tid];
        f16x2 xa = __builtin_bit_cast(f16x2, xv.x);
        f16x2 xb = __builtin_bit_cast(f16x2, xv.y);
        float zi = a0 + p0[0] + p1[0] + p2[0] + p3[0] + (float)xa[0];
        float zj = a1 + p0[1] + p1[1] + p2[1] + p3[1] + (float)xa[1];
        float zf = a2 + p0[2] + p1[2] + p2[2] + p3[2] + (float)xb[0];
        float zo = a3 + p0[3] + p1[3] + p2[3] + p3[3] + (float)xb[1];
        c = c * sigm(zf) + sigm(zi) * tanh_fast(zj);
        float h = tanh_fast(c) * sigm(zo);
        unsigned short hh = f2h(h);
        last_h = hh;
        himg[cur ^ 1][tid] = hh;
        hist[sl*200 + tid] = hh;
      }
      cur ^= 1;
      __syncthreads();   // new h visible for next step
    }
    prev_tb = tb; prev_cnt = cnt; buf ^= 1;
  }
  // final flush + state save
  if (prev_tb >= 0) {
    int pcnt = prev_cnt;
    if (tid < pcnt * 25) {
      int srow = dir ? (pcnt - 1 - tid / 25) : (tid / 25);
      uint4 v = *(const uint4*)&hist[srow*200 + (tid % 25)*8];
      size_t base = dir ? ((size_t)(b*T_LEN + (L - prev_tb - pcnt)))*HH
                        : ((size_t)(b*T_LEN + prev_tb))*HH;
      *(uint4*)(Hd + base + (size_t)tid*8) = v;
    }
  }
  if (tid < 200) {
    cState[ch * HH + tid] = c;
    hState[ch * HH + tid] = last_h;
  }
}

// ---------------- logits = [fwH|bwH] @ Wd + bd
__global__ __launch_bounds__(256) void out_kernel(
    const unsigned short* __restrict__ fwH, const unsigned short* __restrict__ bwH,
    const float* __restrict__ Wd, const float* __restrict__ bd, float* __restrict__ out)
{
  __shared__ float wd[2000];
  int tid = threadIdx.x;
  for (int i = tid; i < 2000; i += 256) wd[i] = Wd[i];
  __syncthreads();
  int row = blockIdx.x * 256 + tid;
  float acc0 = bd[0], acc1 = bd[1], acc2 = bd[2], acc3 = bd[3], acc4 = bd[4];
  const unsigned int* fu = (const unsigned int*)(fwH + (size_t)row * HH);
  const unsigned int* bu = (const unsigned int*)(bwH + (size_t)row * HH);
  #pragma unroll 4
  for (int i = 0; i < 100; ++i) {
    f16x2 pf = __builtin_bit_cast(f16x2, fu[i]);
    f16x2 pb = __builtin_bit_cast(f16x2, bu[i]);
    int k = 2 * i;
    float f0 = (float)pf[0], f1 = (float)pf[1];
    float b0 = (float)pb[0], b1 = (float)pb[1];
    const float* w0 = &wd[k*5];
    const float* w1 = &wd[(k+1)*5];
    const float* w2 = &wd[(200+k)*5];
    const float* w3 = &wd[(201+k)*5];
    acc0 += f0*w0[0] + f1*w1[0] + b0*w2[0] + b1*w3[0];
    acc1 += f0*w0[1] + f1*w1[1] + b0*w2[1] + b1*w3[1];
    acc2 += f0*w0[2] + f1*w1[2] + b0*w2[2] + b1*w3[2];
    acc3 += f0*w0[3] + f1*w1[3] + b0*w2[3] + b1*w3[3];
    acc4 += f0*w0[4] + f1*w1[4] + b0*w2[4] + b1*w3[4];
  }
  float* o = out + (size_t)row * 5;
  o[0]=acc0; o[1]=acc1; o[2]=acc2; o[3]=acc3; o[4]=acc4;
}

extern "C" void kernel_launch(void* const* d_in, const int* in_sizes, int n_in,
                              void* d_out, int out_size, void* d_ws, size_t ws_size,
                              hipStream_t stream)
{
  const float* signals = (const float*)d_in[0];
  const int*   lens    = (const int*)  d_in[1];
  const float* k1w     = (const float*)d_in[2];
  const float* k1aw    = (const float*)d_in[3];
  const float* k1ab    = (const float*)d_in[4];
  const float* k2w     = (const float*)d_in[5];
  const float* k3w     = (const float*)d_in[6];
  const float* Wf      = (const float*)d_in[7];
  const float* bf      = (const float*)d_in[8];
  const float* Wb      = (const float*)d_in[9];
  const float* bb      = (const float*)d_in[10];
  const float* Wd      = (const float*)d_in[11];
  const float* bd      = (const float*)d_in[12];
  float* out = (float*)d_out;
  char* ws = (char*)d_ws;

  // Region A aliases C2 (conv phase) and XWbuf (LSTM phase) — disjoint lifetimes.
  size_t szC2   = (size_t)NROWS * 256 * 2;          // 33,554,432
  size_t szXWb  = (size_t)64 * TB * 800 * 2;        // 26,214,400
  size_t szA    = (szC2 > szXWb) ? szC2 : szXWb;
  size_t oA   = 0;
  size_t oE   = oA   + szA;
  size_t oFw  = oE   + (size_t)NROWS*256*2;
  size_t oBw  = oFw  + (size_t)NROWS*HH*2;
  size_t oWhK = oBw  + (size_t)NROWS*HH*2;
  size_t oWx2 = oWhK + (size_t)320000*2;            // 640,000
  size_t oK3  = oWx2 + (size_t)2*256*800*2;
  size_t oPQ  = oK3  + (size_t)256*256*2;
  size_t oBc  = oPQ  + 1536*4;
  size_t oCst = oBc  + 1600*4;
  size_t oHst = oCst + (size_t)64*HH*4;
  size_t total= oHst + (size_t)64*HH*2;
  if (ws_size < total) return;

  unsigned short* C2    = (unsigned short*)(ws + oA);
  unsigned short* XWbuf = (unsigned short*)(ws + oA);
  unsigned short* E     = (unsigned short*)(ws + oE);
  unsigned short* fwH   = (unsigned short*)(ws + oFw);
  unsigned short* bwH   = (unsigned short*)(ws + oBw);
  unsigned short* WhK   = (unsigned short*)(ws + oWhK);
  unsigned short* Wx2   = (unsigned short*)(ws + oWx2);
  unsigned short* K3h   = (unsigned short*)(ws + oK3);
  float* PQ     = (float*)(ws + oPQ);
  float* bcat   = (float*)(ws + oBc);
  float* cState = (float*)(ws + oCst);
  unsigned short* hState = (unsigned short*)(ws + oHst);

  (void)hipMemsetAsync(fwH, 0, (size_t)2*NROWS*HH*2, stream);
  pq_kernel  <<<6,     256, 0, stream>>>(k1w, k2w, PQ);
  prep_kernel<<<3113,  256, 0, stream>>>(k3w, Wf, bf, Wb, bb, K3h, Wx2, WhK, bcat);
  conv2_kernel<<<NROWS, 256, 0, stream>>>(signals, PQ, C2);
  gemm_kernel<<<1024,  256, 0, stream>>>(C2, K3h, 256, 2, 0, E, nullptr, signals, k1aw, k1ab, nullptr, 0);
  for (int t0 = 0; t0 < T_LEN; t0 += TB) {
    gemm_kernel<<<896, 256, 0, stream>>>(E, Wx2, 800, 7, 2, XWbuf, bcat, nullptr, nullptr, nullptr, lens, t0);
    lstm_kernel<<<64, 1024, 0, stream>>>(XWbuf, WhK, lens, fwH, bwH, cState, hState, t0);
  }
  out_kernel <<<256,   256, 0, stream>>>(fwH, bwH, Wd, bd, out);
}